// Round 6
// baseline (99.999 us; speedup 1.0000x reference)
//
#include <hip/hip_runtime.h>

namespace {

constexpr int JN = 21;   // joints
constexpr int BN = 20;   // bones
constexpr int FR = 64;   // frames per block

constexpr float F_F  = 512.0f;
constexpr float PX_F = 512.0f;
constexpr float PY_F = 288.0f;
constexpr float EPS_F = 1e-8f;

// weights folded with per-loss divisors
constexpr float WPROJ   = 0.25f / (2.0f * 21.0f);
constexpr float WLIFT   = 0.25f / (3.0f * 21.0f);
constexpr float WBONE   = 0.25f / 20.0f;
constexpr float WSMOOTH = 0.25f / (3.0f * 21.0f);

__device__ __forceinline__ double block_reduce(double val) {
    __shared__ double smem[16];
    const int lane = threadIdx.x & 63;
    const int wid  = threadIdx.x >> 6;
    #pragma unroll
    for (int off = 32; off > 0; off >>= 1)
        val += __shfl_down(val, off, 64);
    if (lane == 0) smem[wid] = val;
    __syncthreads();
    if (wid == 0) {
        const int nw = blockDim.x >> 6;
        val = (lane < nw) ? smem[lane] : 0.0;
        #pragma unroll
        for (int off = 32; off > 0; off >>= 1)
            val += __shfl_down(val, off, 64);
    }
    return val;
}

__global__ __launch_bounds__(256, 4) void pose_loss_kernel(
    const float* __restrict__ pose3d,      // (W+1, 3, 21)
    const float* __restrict__ bone_2d,     // (W, 2, 21)
    const float* __restrict__ lift_dirs,   // (W, 3, 20)
    const float* __restrict__ R_drone,     // (W, 3, 3)
    const float* __restrict__ C_drone,     // (W, 3, 1)
    const float* __restrict__ bone_len,    // (20,)
    const float* __restrict__ R_cam,       // (3,3)
    float* __restrict__ partials,          // (gridDim.x,)
    unsigned int* __restrict__ counter,    // zeroed before launch
    float* __restrict__ out,
    int W)
{
    // 4162 + 576 + 192 floats = 19.7 KB
    __shared__ alignas(16) float s_pose[(FR + 2) * 63 + 2];
    __shared__ alignas(16) float s_M[FR * 9];
    __shared__ alignas(16) float s_MC[FR * 3];
    __shared__ unsigned int s_isLast;

    const int tid = threadIdx.x;
    const int w0  = blockIdx.x * FR;
    const int nF  = min(FR, W - w0);
    const int nPoseF = min(FR + 2, W + 1 - w0);
    const bool full = (nF == FR);

    // ---------- 1) prefetch read-once streams into registers (issued FIRST) ----------
    float bu[6], bv[6], l0[6], l1[6], l2[6];
    if (full) {
        #pragma unroll
        for (int k = 0; k < 6; ++k) {
            if (k < 5 || tid < FR * JN - 5 * 256) {
                const int idx = k * 256 + tid;
                const int wl = idx / JN;
                const int j  = idx - wl * JN;
                const size_t w = (size_t)(w0 + wl);
                bu[k] = bone_2d[w * 42 + j];
                bv[k] = bone_2d[w * 42 + JN + j];
                if (j < BN) {
                    l0[k] = lift_dirs[w * 60 + j];
                    l1[k] = lift_dirs[w * 60 + BN + j];
                    l2[k] = lift_dirs[w * 60 + 2 * BN + j];
                }
            }
        }
    }

    // ---------- 2) stage reused data (pose halo, R, C) with float4 loads ----------
    {
        const float* src = pose3d + (size_t)w0 * 63;
        const int nfl = nPoseF * 63;
        const int n4 = nfl >> 2;
        const float4* s4 = (const float4*)src;
        float4* d4 = (float4*)s_pose;
        for (int i = tid; i < n4; i += 256) d4[i] = s4[i];
        for (int i = (n4 << 2) + tid; i < nfl; i += 256) s_pose[i] = src[i];
    }
    {
        const float* src = R_drone + (size_t)w0 * 9;
        const int n4 = (nF * 9) >> 2;
        const float4* s4 = (const float4*)src;
        float4* d4 = (float4*)s_M;
        for (int i = tid; i < n4; i += 256) d4[i] = s4[i];
        for (int i = (n4 << 2) + tid; i < nF * 9; i += 256) s_M[i] = src[i];
    }
    {
        const float* src = C_drone + (size_t)w0 * 3;
        const int n4 = (nF * 3) >> 2;
        const float4* s4 = (const float4*)src;
        float4* d4 = (float4*)s_MC;
        for (int i = tid; i < n4; i += 256) d4[i] = s4[i];
        for (int i = (n4 << 2) + tid; i < nF * 3; i += 256) s_MC[i] = src[i];
    }
    __syncthreads();

    // ---------- 3) per-frame precompute: M = R_cam @ Rd^T, MC = M @ C ----------
    if (tid < nF) {
        float Rd[9];
        #pragma unroll
        for (int k = 0; k < 9; ++k) Rd[k] = s_M[tid * 9 + k];
        float rc[9];
        #pragma unroll
        for (int k = 0; k < 9; ++k) rc[k] = R_cam[k];   // uniform -> s_load
        float M[9];
        #pragma unroll
        for (int i = 0; i < 3; ++i)
            #pragma unroll
            for (int k = 0; k < 3; ++k)
                M[i * 3 + k] = rc[i * 3 + 0] * Rd[k * 3 + 0]
                             + rc[i * 3 + 1] * Rd[k * 3 + 1]
                             + rc[i * 3 + 2] * Rd[k * 3 + 2];
        const float C0 = s_MC[tid * 3 + 0];
        const float C1 = s_MC[tid * 3 + 1];
        const float C2 = s_MC[tid * 3 + 2];
        #pragma unroll
        for (int k = 0; k < 9; ++k) s_M[tid * 9 + k] = M[k];
        #pragma unroll
        for (int i = 0; i < 3; ++i)
            s_MC[tid * 3 + i] = M[i * 3 + 0] * C0 + M[i * 3 + 1] * C1 + M[i * 3 + 2] * C2;
    }
    __syncthreads();

    // ---------- 4) compute: pose/M/MC from LDS, streams from registers ----------
    float partial = 0.0f;

    auto item = [&](int idx, float buk, float bvk, float l0k, float l1k, float l2k) {
        const int wl = idx / JN;
        const int j  = idx - wl * JN;
        const int w  = w0 + wl;

        const float* P1 = s_pose + (wl + 1) * 63;   // frame w+1
        const float p1x = P1[j];
        const float p1y = P1[JN + j];
        const float p1z = P1[2 * JN + j];

        // projection loss
        {
            const float* M  = s_M  + wl * 9;
            const float* MC = s_MC + wl * 3;
            const float c0 = M[0] * p1x + M[1] * p1y + M[2] * p1z - MC[0];
            const float c1 = M[3] * p1x + M[4] * p1y + M[5] * p1z - MC[1];
            const float c2 = M[6] * p1x + M[7] * p1y + M[8] * p1z - MC[2];
            const float invz = 1.0f / c2;
            const float u = F_F * c0 * invz + PX_F;
            const float v = F_F * c1 * invz + PY_F;
            const float du = u - buk;
            const float dv = v - bvk;
            partial += WPROJ * (du * du + dv * dv);
        }

        // lift + bone losses; bone_connections is statically (j+1, j)
        if (j < BN) {
            const int b0 = j + 1;
            const int b1 = j;
            {
                const float ax = P1[b0]          - P1[b1];
                const float ay = P1[JN + b0]     - P1[JN + b1];
                const float az = P1[2 * JN + b0] - P1[2 * JN + b1];
                const float inv = 1.0f / (sqrtf(ax * ax + ay * ay + az * az) + EPS_F);
                const float lx = l0k - ax * inv;
                const float ly = l1k - ay * inv;
                const float lz = l2k - az * inv;
                partial += WLIFT * (lx * lx + ly * ly + lz * lz);
            }
            const float blj = bone_len[j];
            {
                const float* P0 = s_pose + wl * 63;   // frame w
                const float bx = P0[b0]          - P0[b1];
                const float by = P0[JN + b0]     - P0[JN + b1];
                const float bz = P0[2 * JN + b0] - P0[2 * JN + b1];
                const float bl = bx * bx + by * by + bz * bz;
                const float e = blj - bl;
                partial += WBONE * (e * e);
            }
            if (w == W - 1) {                         // frame W == P1 here
                const float bx = P1[b0]          - P1[b1];
                const float by = P1[JN + b0]     - P1[JN + b1];
                const float bz = P1[2 * JN + b0] - P1[2 * JN + b1];
                const float bl = bx * bx + by * by + bz * bz;
                const float e = blj - bl;
                partial += WBONE * (e * e);
            }
        }

        // smoothness (t = w)
        if (w < W - 1) {
            const float* P0 = s_pose + wl * 63;
            const float* P2 = s_pose + (wl + 2) * 63;
            const float sx = P2[j]          - 2.0f * p1x + P0[j];
            const float sy = P2[JN + j]     - 2.0f * p1y + P0[JN + j];
            const float sz = P2[2 * JN + j] - 2.0f * p1z + P0[2 * JN + j];
            partial += WSMOOTH * (sx * sx + sy * sy + sz * sz);
        }
    };

    if (full) {
        #pragma unroll
        for (int k = 0; k < 6; ++k) {
            if (k < 5 || tid < FR * JN - 5 * 256)
                item(k * 256 + tid, bu[k], bv[k], l0[k], l1[k], l2[k]);
        }
    } else {
        for (int idx = tid; idx < nF * JN; idx += 256) {
            const int wl = idx / JN;
            const int j  = idx - wl * JN;
            const size_t w = (size_t)(w0 + wl);
            const float xbu = bone_2d[w * 42 + j];
            const float xbv = bone_2d[w * 42 + JN + j];
            float xl0 = 0.f, xl1 = 0.f, xl2 = 0.f;
            if (j < BN) {
                xl0 = lift_dirs[w * 60 + j];
                xl1 = lift_dirs[w * 60 + BN + j];
                xl2 = lift_dirs[w * 60 + 2 * BN + j];
            }
            item(idx, xbu, xbv, xl0, xl1, xl2);
        }
    }

    const double bsum = block_reduce((double)partial);

    // ---------- 5) fused final reduction: last-block-done ----------
    if (tid == 0) {
        __hip_atomic_store(&partials[blockIdx.x], (float)bsum,
                           __ATOMIC_RELEASE, __HIP_MEMORY_SCOPE_AGENT);
        const unsigned int c = __hip_atomic_fetch_add(counter, 1u,
                           __ATOMIC_ACQ_REL, __HIP_MEMORY_SCOPE_AGENT);
        s_isLast = (c == gridDim.x - 1) ? 1u : 0u;
    }
    __syncthreads();
    if (s_isLast) {
        double v = 0.0;
        for (int i = tid; i < (int)gridDim.x; i += 256)
            v += (double)__hip_atomic_load(&partials[i],
                           __ATOMIC_ACQUIRE, __HIP_MEMORY_SCOPE_AGENT);
        v = block_reduce(v);
        if (tid == 0) out[0] = (float)v;
    }
}

}  // namespace

extern "C" void kernel_launch(void* const* d_in, const int* in_sizes, int n_in,
                              void* d_out, int out_size, void* d_ws, size_t ws_size,
                              hipStream_t stream) {
    const float* pose3d    = (const float*)d_in[0];
    const float* bone_2d   = (const float*)d_in[1];
    const float* lift_dirs = (const float*)d_in[2];
    const float* R_drone   = (const float*)d_in[3];
    const float* C_drone   = (const float*)d_in[4];
    const float* bone_len  = (const float*)d_in[5];
    const float* R_cam     = (const float*)d_in[6];
    float* out = (float*)d_out;

    const int W = in_sizes[3] / 9;       // R_drone is (W,3,3)
    const int grid = (W + FR - 1) / FR;  // 2048 for W=131072

    float* partials = (float*)d_ws;
    unsigned int* counter = (unsigned int*)((char*)d_ws + ((size_t)grid * 4 + 255) / 256 * 256);

    hipMemsetAsync(counter, 0, sizeof(unsigned int), stream);

    pose_loss_kernel<<<grid, 256, 0, stream>>>(
        pose3d, bone_2d, lift_dirs, R_drone, C_drone, bone_len, R_cam,
        partials, counter, out, W);
}

// Round 7
// 27.157 us; speedup vs baseline: 3.6822x; 3.6822x over previous
//
#include <hip/hip_runtime.h>

namespace {

constexpr int JN = 21;    // joints
constexpr int BN = 20;    // bones
constexpr int FR = 64;    // frames per block
constexpr int HT = 32;    // half-tile frames
constexpr int SPLIT0 = 36; // pose frames staged in chunk0 (36*63 floats, 16B-aligned split)

constexpr float F_F  = 512.0f;
constexpr float PX_F = 512.0f;
constexpr float PY_F = 288.0f;
constexpr float EPS_F = 1e-8f;

// weights folded with per-loss divisors
constexpr float WPROJ   = 0.25f / (2.0f * 21.0f);
constexpr float WLIFT   = 0.25f / (3.0f * 21.0f);
constexpr float WBONE   = 0.25f / 20.0f;
constexpr float WSMOOTH = 0.25f / (3.0f * 21.0f);

__device__ __forceinline__ double block_reduce(double val) {
    __shared__ double smem[16];
    const int lane = threadIdx.x & 63;
    const int wid  = threadIdx.x >> 6;
    #pragma unroll
    for (int off = 32; off > 0; off >>= 1)
        val += __shfl_down(val, off, 64);
    if (lane == 0) smem[wid] = val;
    __syncthreads();
    if (wid == 0) {
        const int nw = blockDim.x >> 6;
        val = (lane < nw) ? smem[lane] : 0.0;
        #pragma unroll
        for (int off = 32; off > 0; off >>= 1)
            val += __shfl_down(val, off, 64);
    }
    return val;
}

__global__ __launch_bounds__(256) void pose_loss_kernel(
    const float* __restrict__ pose3d,      // (W+1, 3, 21)
    const float* __restrict__ bone_2d,     // (W, 2, 21)
    const float* __restrict__ lift_dirs,   // (W, 3, 20)
    const float* __restrict__ R_drone,     // (W, 3, 3)
    const float* __restrict__ C_drone,     // (W, 3, 1)
    const float* __restrict__ bone_len,    // (20,)
    const float* __restrict__ R_cam,       // (3,3)
    float* __restrict__ partials,          // (gridDim.x,)
    int W)
{
    // 4162 + 576 + 192 floats = 19.7 KB -> 8 blocks/CU by LDS
    __shared__ alignas(16) float s_pose[(FR + 2) * 63 + 2];
    __shared__ alignas(16) float s_M[FR * 9];
    __shared__ alignas(16) float s_MC[FR * 3];

    const int tid = threadIdx.x;
    const int w0  = blockIdx.x * FR;
    const int nF  = min(FR, W - w0);
    const int nPoseF = min(FR + 2, W + 1 - w0);

    // coop float4 stage (both src and dst 16B-aligned by construction)
    auto stage4 = [&](float* dst, const float* src, int nfl) {
        const int n4 = nfl >> 2;
        const float4* s4 = (const float4*)src;
        float4* d4 = (float4*)dst;
        for (int i = tid; i < n4; i += 256) d4[i] = s4[i];
        for (int i = (n4 << 2) + tid; i < nfl; i += 256) dst[i] = src[i];
    };

    // per-frame M = R_cam @ Rd^T, MC = M @ C for frames [base, base+HT), on lanes 0..31
    auto computeM = [&](int base) {
        const int f = base + tid;
        if (tid < HT && f < nF) {
            const float* Rd = R_drone + (size_t)(w0 + f) * 9;
            float rd[9];
            #pragma unroll
            for (int k = 0; k < 9; ++k) rd[k] = Rd[k];
            float rc[9];
            #pragma unroll
            for (int k = 0; k < 9; ++k) rc[k] = R_cam[k];   // uniform -> s_load
            float M[9];
            #pragma unroll
            for (int i = 0; i < 3; ++i)
                #pragma unroll
                for (int k = 0; k < 3; ++k)
                    M[i * 3 + k] = rc[i * 3 + 0] * rd[k * 3 + 0]
                                 + rc[i * 3 + 1] * rd[k * 3 + 1]
                                 + rc[i * 3 + 2] * rd[k * 3 + 2];
            const float* Cp = C_drone + (size_t)(w0 + f) * 3;
            const float C0 = Cp[0], C1 = Cp[1], C2 = Cp[2];
            #pragma unroll
            for (int k = 0; k < 9; ++k) s_M[f * 9 + k] = M[k];
            #pragma unroll
            for (int i = 0; i < 3; ++i)
                s_MC[f * 3 + i] = M[i * 3 + 0] * C0 + M[i * 3 + 1] * C1 + M[i * 3 + 2] * C2;
        }
    };

    float partial = 0.0f;

    auto item = [&](int wl, int j) {
        const int w = w0 + wl;

        const float* P1 = s_pose + (wl + 1) * 63;   // frame w+1
        const float p1x = P1[j];
        const float p1y = P1[JN + j];
        const float p1z = P1[2 * JN + j];

        // projection loss (streams bone_2d)
        {
            const float* M  = s_M  + wl * 9;
            const float* MC = s_MC + wl * 3;
            const float c0 = M[0] * p1x + M[1] * p1y + M[2] * p1z - MC[0];
            const float c1 = M[3] * p1x + M[4] * p1y + M[5] * p1z - MC[1];
            const float c2 = M[6] * p1x + M[7] * p1y + M[8] * p1z - MC[2];
            const float invz = 1.0f / c2;
            const float u = F_F * c0 * invz + PX_F;
            const float v = F_F * c1 * invz + PY_F;
            const float du = u - bone_2d[(size_t)w * 42 + j];
            const float dv = v - bone_2d[(size_t)w * 42 + JN + j];
            partial += WPROJ * (du * du + dv * dv);
        }

        // lift + bone losses; bone_connections is statically (j+1, j)
        if (j < BN) {
            const int b0 = j + 1;
            const int b1 = j;
            {
                const float ax = P1[b0]          - P1[b1];
                const float ay = P1[JN + b0]     - P1[JN + b1];
                const float az = P1[2 * JN + b0] - P1[2 * JN + b1];
                const float inv = 1.0f / (sqrtf(ax * ax + ay * ay + az * az) + EPS_F);
                const float lx = lift_dirs[(size_t)w * 60 + j]          - ax * inv;
                const float ly = lift_dirs[(size_t)w * 60 + BN + j]     - ay * inv;
                const float lz = lift_dirs[(size_t)w * 60 + 2 * BN + j] - az * inv;
                partial += WLIFT * (lx * lx + ly * ly + lz * lz);
            }
            const float blj = bone_len[j];
            {
                const float* P0 = s_pose + wl * 63;   // frame w
                const float bx = P0[b0]          - P0[b1];
                const float by = P0[JN + b0]     - P0[JN + b1];
                const float bz = P0[2 * JN + b0] - P0[2 * JN + b1];
                const float bl = bx * bx + by * by + bz * bz;
                const float e = blj - bl;
                partial += WBONE * (e * e);
            }
            if (w == W - 1) {                         // frame W == P1 here
                const float bx = P1[b0]          - P1[b1];
                const float by = P1[JN + b0]     - P1[JN + b1];
                const float bz = P1[2 * JN + b0] - P1[2 * JN + b1];
                const float bl = bx * bx + by * by + bz * bz;
                const float e = blj - bl;
                partial += WBONE * (e * e);
            }
        }

        // smoothness (t = w)
        if (w < W - 1) {
            const float* P0 = s_pose + wl * 63;
            const float* P2 = s_pose + (wl + 2) * 63;
            const float sx = P2[j]          - 2.0f * p1x + P0[j];
            const float sy = P2[JN + j]     - 2.0f * p1y + P0[JN + j];
            const float sz = P2[2 * JN + j] - 2.0f * p1z + P0[2 * JN + j];
            partial += WSMOOTH * (sx * sx + sy * sy + sz * sz);
        }
    };

    // ---------------- prologue: stage chunk0 (frames [0,36)) + M for [0,32) ----------------
    {
        const int f1 = min(SPLIT0, nPoseF);
        stage4(s_pose, pose3d + (size_t)w0 * 63, f1 * 63);
        computeM(0);
    }
    __syncthreads();

    // ---------------- pipelined phase: stage chunk1 + M[32,64) overlapped with tile0 ----------------
    if (nPoseF > SPLIT0) {
        stage4(s_pose + SPLIT0 * 63, pose3d + ((size_t)w0 + SPLIT0) * 63,
               (nPoseF - SPLIT0) * 63);
    }
    computeM(HT);

    {
        const int nItems0 = min(HT, nF) * JN;   // tile0: wl in [0,32)
        for (int it = tid; it < nItems0; it += 256) {
            const int wl = it / JN;
            const int j  = it - wl * JN;
            item(wl, j);
        }
    }
    __syncthreads();

    // ---------------- tile1: wl in [32, nF) ----------------
    if (nF > HT) {
        const int nItems1 = (nF - HT) * JN;
        for (int it = tid; it < nItems1; it += 256) {
            const int wl = HT + it / JN;
            const int j  = it - (it / JN) * JN;
            item(wl, j);
        }
    }

    const double bsum = block_reduce((double)partial);
    if (tid == 0) partials[blockIdx.x] = (float)bsum;
}

__global__ __launch_bounds__(256) void final_reduce_kernel(
    const float* __restrict__ partials, float* __restrict__ out, int n)
{
    double v = 0.0;
    for (int i = threadIdx.x; i < n; i += blockDim.x)
        v += (double)partials[i];
    v = block_reduce(v);
    if (threadIdx.x == 0) out[0] = (float)v;
}

}  // namespace

extern "C" void kernel_launch(void* const* d_in, const int* in_sizes, int n_in,
                              void* d_out, int out_size, void* d_ws, size_t ws_size,
                              hipStream_t stream) {
    const float* pose3d    = (const float*)d_in[0];
    const float* bone_2d   = (const float*)d_in[1];
    const float* lift_dirs = (const float*)d_in[2];
    const float* R_drone   = (const float*)d_in[3];
    const float* C_drone   = (const float*)d_in[4];
    const float* bone_len  = (const float*)d_in[5];
    const float* R_cam     = (const float*)d_in[6];
    float* out = (float*)d_out;
    float* partials = (float*)d_ws;

    const int W = in_sizes[3] / 9;       // R_drone is (W,3,3)
    const int grid = (W + FR - 1) / FR;  // 2048 for W=131072

    pose_loss_kernel<<<grid, 256, 0, stream>>>(
        pose3d, bone_2d, lift_dirs, R_drone, C_drone, bone_len, R_cam, partials, W);
    final_reduce_kernel<<<1, 256, 0, stream>>>(partials, out, grid);
}